// Round 4
// baseline (91.675 us; speedup 1.0000x reference)
//
#include <hip/hip_runtime.h>

// Problem constants (reference: B=4, N=8192, PIXEL_DIM=3).
#define BB   4
#define NN   8192
#define BN   (BB * NN)
#define TPB  256

#define QW    64               // queries per wave (4 MFMA col-tiles)
#define QBLK  (QW * 4)         // 256 queries per block (4 waves)
#define KSTEP 32               // keys per inner step

// f16-scale Schraudolph: u = QS16*(q.k + q.bk) + B16C; f16 bits = u16(sat_u32(u)).
// QS16 = 1024*log2(e)/sqrt(3); B16C = (15 - 8 - 0.03546)*1024. The 2^-8.04 scale
// on p and the interp-error systematic part cancel in G/L. Validated rounds 1-2
// (absmax 0.015625). u stays ~[0, ~21k]: < 31744 (f16 inf) and < 65536 (u16),
// negatives saturate to 0 via v_cvt_u32_f32.
#define QS16  852.58618f
#define B16C  7131.651f

typedef _Float16 f16;
typedef f16   f16x4 __attribute__((ext_vector_type(4)));
typedef f16   f16x8 __attribute__((ext_vector_type(8)));
typedef float f32x4 __attribute__((ext_vector_type(4)));

union H8 { f16x8 v; f16x4 h[2]; unsigned u[4]; };

// pack low halves of two cvt results into one VGPR of 2 f16 bit-patterns
__device__ __forceinline__ unsigned pkbits(unsigned lo, unsigned hi) {
    return __builtin_amdgcn_perm(hi, lo, 0x05040100); // bytes lo.0,lo.1,hi.0,hi.1
}

// ---------------------------------------------------------------------------
// Swapped-operand MFMA attention partials (no P round-trip through LDS),
// QW=64: 4 query col-tiles per wave amortize the K/V LDS reads 2x vs QW=32.
//   QK^T (swapped): S = mfma(A=K rows, B=Q cols, C=seed) -> D[key][query]:
//     lane holds col=query(lane&15), rows=keys 4ch+r; each lane owns 8 scores
//     of ONE query row = exactly the PV A-fragment ownership.
//   exp: v_cvt_u32_f32 (saturating) + v_perm pack -> PV A-frag in registers.
//   PV: G[t] += mfma(PA[t], V', G[t]) with k-slot permutation sigma(ch,s):
//     slots 0-3 = keys kk+4ch..+3, slots 4-7 = keys kk+16+4ch..+3, matched on
//     the B side by two ds_read_b64 from comp-major KTlds (pad +8 -> <=2-way).
//   Accumulator cols 0..3 = (L, G0, G1, G2); col 0 via V' comp row of ones.
// Fragment layouts identical to rounds 1-2 (validated):
//   A: row=lane&15, k=8ch+slot;  B: col=lane&15, k=8ch+slot;
//   C/D: col=lane&15, row=4ch+reg.
// Per 32-key step (64 q): 12 MFMA, 32 cvt, 16 perm, 4 ds_read_b64 (no conflict).
// LDS = SEGK*8 + 4*(SEGK+8)*2 bytes (16.4 KB at SEGK=1024) -> 4 blocks/CU at
// grid 1024, 16 waves/CU.
// ---------------------------------------------------------------------------
template <int SEGK_T>
__global__ __launch_bounds__(TPB) void attn_mfma_kernel(
    const float* __restrict__ x, const float* __restrict__ W,
    const float* __restrict__ bias, float4* __restrict__ part)
{
    __shared__ f16x4 Klds[SEGK_T];           // (x0,x1,x2,0) per key : QK A-frag
    __shared__ f16   KTlds[4][SEGK_T + 8];   // comps {1,x0,x1,x2}   : PV B-frag

    const int tid  = threadIdx.x;
    const int lane = tid & 63;
    const int w    = tid >> 6;
    const int seg  = blockIdx.x;
    const int qt   = blockIdx.y;
    const int b    = blockIdx.z;

    // ---- stage keys to LDS (f16) — round-2-validated scalar path ----
    const float* kbp = x + ((size_t)b * NN + (size_t)seg * SEGK_T) * 3;
    for (int i = tid; i < SEGK_T; i += TPB) {
        float k0 = kbp[3 * i], k1 = kbp[3 * i + 1], k2 = kbp[3 * i + 2];
        f16 h0 = (f16)k0, h1 = (f16)k1, h2 = (f16)k2;
        Klds[i] = (f16x4){h0, h1, h2, (f16)0.f};
        KTlds[0][i] = (f16)1.f;
        KTlds[1][i] = h0;
        KTlds[2][i] = h1;
        KTlds[3][i] = h2;
    }

    // ---- per-query prep: each lane carries query q0i + lane ----
    float Wr[9][3], br[9];
#pragma unroll
    for (int c = 0; c < 9; ++c) {
        Wr[c][0] = W[3 * c]; Wr[c][1] = W[3 * c + 1]; Wr[c][2] = W[3 * c + 2];
        br[c] = bias[c];
    }
    const int q0i = qt * QBLK + w * QW;
    float qcs;                 // QS16*(q.bk) + B16C
    unsigned qp0, qp1;         // packed f16 {QS16*qt0, qt1}, {qt2, 0}
    {
        const float* xq = x + ((size_t)b * NN + q0i + lane) * 3;
        float x0 = xq[0], x1 = xq[1], x2 = xq[2];
        float a0 = fmaf(x0, Wr[0][0], fmaf(x1, Wr[0][1], fmaf(x2, Wr[0][2], br[0])));
        float a1 = fmaf(x0, Wr[3][0], fmaf(x1, Wr[3][1], fmaf(x2, Wr[3][2], br[3])));
        float a2 = fmaf(x0, Wr[6][0], fmaf(x1, Wr[6][1], fmaf(x2, Wr[6][2], br[6])));
        float t0 = QS16 * fmaf(a0, Wr[1][0], fmaf(a1, Wr[4][0], a2 * Wr[7][0]));
        float t1 = QS16 * fmaf(a0, Wr[1][1], fmaf(a1, Wr[4][1], a2 * Wr[7][1]));
        float t2 = QS16 * fmaf(a0, Wr[1][2], fmaf(a1, Wr[4][2], a2 * Wr[7][2]));
        qcs = fmaf(QS16, fmaf(a0, br[1], fmaf(a1, br[4], a2 * br[7])), B16C);
        f16x4 qh = (f16x4){(f16)t0, (f16)t1, (f16)t2, (f16)0.f};
        unsigned up[2];
        __builtin_memcpy(up, &qh, 8);
        qp0 = up[0]; qp1 = up[1];
    }

    const int li = lane & 15, ch = lane >> 4;

    // Q B-frags (hoisted, loop-invariant): tile t covers queries 16t..16t+15;
    // col=query li, ch=0 slots 0..2 = scaled comps, everything else zero.
    // C-seed: all regs = qcs(query 16t+li).
    H8 Bq[4];
    f32x4 qC[4];
#pragma unroll
    for (int t = 0; t < 4; ++t) {
        int src = 16 * t + li;
        unsigned a0 = (unsigned)__shfl((int)qp0, src);
        unsigned a1 = (unsigned)__shfl((int)qp1, src);
        if (ch != 0) { a0 = 0u; a1 = 0u; }
        Bq[t].u[0] = a0; Bq[t].u[1] = a1; Bq[t].u[2] = 0u; Bq[t].u[3] = 0u;
        float cs = __shfl(qcs, src);
        qC[t] = (f32x4){cs, cs, cs, cs};
    }

    __syncthreads();

    const f16x4* Ka    = &Klds[li];                 // A-frag rows
    const f16*   Vbase = &KTlds[lane & 3][4 * ch];  // PV B-frag (cols>=4 dup)

    f32x4 G[4];
#pragma unroll
    for (int t = 0; t < 4; ++t) G[t] = (f32x4){0.f, 0.f, 0.f, 0.f};

#pragma unroll 1
    for (int kk = 0; kk < SEGK_T; kk += KSTEP) {
        H8 A0, A1, V;
        A0.h[0] = Ka[kk];      A0.u[2] = 0u; A0.u[3] = 0u;
        A1.h[0] = Ka[kk + 16]; A1.u[2] = 0u; A1.u[3] = 0u;
        V.h[0] = *(const f16x4*)(Vbase + kk);        // sigma slots 0-3
        V.h[1] = *(const f16x4*)(Vbase + kk + 16);   // sigma slots 4-7

#pragma unroll
        for (int t = 0; t < 4; ++t) {
            f32x4 S0 = __builtin_amdgcn_mfma_f32_16x16x32_f16(A0.v, Bq[t].v, qC[t], 0, 0, 0);
            f32x4 S1 = __builtin_amdgcn_mfma_f32_16x16x32_f16(A1.v, Bq[t].v, qC[t], 0, 0, 0);
            unsigned u0[4], u1[4];
#pragma unroll
            for (int r = 0; r < 4; ++r) {
                asm("v_cvt_u32_f32 %0, %1" : "=v"(u0[r]) : "v"(S0[r]));
                asm("v_cvt_u32_f32 %0, %1" : "=v"(u1[r]) : "v"(S1[r]));
            }
            H8 PA;
            PA.u[0] = pkbits(u0[0], u0[1]);  PA.u[1] = pkbits(u0[2], u0[3]);
            PA.u[2] = pkbits(u1[0], u1[1]);  PA.u[3] = pkbits(u1[2], u1[3]);
            G[t] = __builtin_amdgcn_mfma_f32_16x16x32_f16(PA.v, V.v, G[t], 0, 0, 0);
        }
    }

    // ---- epilogue: G[t] row=query 16t+4ch+r, col li = (L,G0,G1,G2) ----
    if (li < 4) {
        float* dst = (float*)(part + (size_t)seg * BN + (size_t)b * NN + q0i);
#pragma unroll
        for (int t = 0; t < 4; ++t)
#pragma unroll
            for (int r = 0; r < 4; ++r)
                dst[4 * (16 * t + 4 * ch + r) + li] = G[t][r];
    }
}

// ---------------------------------------------------------------------------
// Combine partials, apply v-projection + residual:
//   out_c = Wv[c] . (G/L) + bv[c] + x_c   (Wv rows = qkv rows 2,5,8).
// ---------------------------------------------------------------------------
template <int NSEG_T>
__global__ __launch_bounds__(128) void combine_kernel(const float4* __restrict__ part,
                                                      const float* __restrict__ x,
                                                      const float* __restrict__ W,
                                                      const float* __restrict__ bias,
                                                      float* __restrict__ out)
{
    int q = blockIdx.x * 128 + threadIdx.x;   // 0 .. BN-1
    float L = 0.f, G0 = 0.f, G1 = 0.f, G2 = 0.f;
#pragma unroll
    for (int s = 0; s < NSEG_T; ++s) {
        float4 p = part[(size_t)s * BN + q];
        L += p.x; G0 += p.y; G1 += p.z; G2 += p.w;
    }
    float inv = 1.0f / L;
    float a0 = G0 * inv, a1 = G1 * inv, a2 = G2 * inv;
#pragma unroll
    for (int c = 0; c < 3; ++c) {
        int r = 3 * c + 2;  // Wv rows 2,5,8
        float o = fmaf(a0, W[3 * r], fmaf(a1, W[3 * r + 1],
                  fmaf(a2, W[3 * r + 2], bias[r])));
        out[3 * q + c] = o + x[3 * q + c];
    }
}

template <int NSEG_T>
static void launch_all(const float* x, const float* W, const float* bias,
                       float4* part, float* out, hipStream_t stream) {
    dim3 g(NSEG_T, NN / QBLK, BB);
    attn_mfma_kernel<NN / NSEG_T><<<g, TPB, 0, stream>>>(x, W, bias, part);
    combine_kernel<NSEG_T><<<BN / 128, 128, 0, stream>>>(part, x, W, bias, out);
}

extern "C" void kernel_launch(void* const* d_in, const int* in_sizes, int n_in,
                              void* d_out, int out_size, void* d_ws, size_t ws_size,
                              hipStream_t stream) {
    const float* x    = (const float*)d_in[0];  // (B, N, 3)
    const float* W    = (const float*)d_in[1];  // (9, 3)
    const float* bias = (const float*)d_in[2];  // (9,)
    float* out = (float*)d_out;                 // (B, N, 3)
    float4* part = (float4*)d_ws;

    size_t plane = (size_t)BN * 16;
    if (ws_size >= 8 * plane)      launch_all<8>(x, W, bias, part, out, stream);
    else                           launch_all<4>(x, W, bias, part, out, stream);
}

// Round 5
// 90.467 us; speedup vs baseline: 1.0133x; 1.0133x over previous
//
#include <hip/hip_runtime.h>

// Problem constants (reference: B=4, N=8192, PIXEL_DIM=3).
#define BB   4
#define NN   8192
#define BN   (BB * NN)
#define TPB  256

#define QW    32               // queries per wave (2 MFMA col-tiles) — round-2 best
#define QBLK  (QW * 4)         // 128 queries per block (4 waves)
#define KSTEP 32               // keys per inner step per stream

// f16-scale Schraudolph: u = QS16*(q.k + q.bk) + B16C; f16 bits = u16(sat_u32(u)).
// QS16 = 1024*log2(e)/sqrt(3); B16C = (15 - 8 - 0.03546)*1024. The 2^-8.04 scale
// on p and the interp-error systematic part cancel in G/L. Validated rounds 1-2
// (absmax 0.015625). u stays < 31744 (f16 inf) and < 65536 (u16); negatives
// saturate to 0 via v_cvt_u32_f32.
#define QS16  852.58618f
#define B16C  7131.651f

typedef _Float16 f16;
typedef f16   f16x4 __attribute__((ext_vector_type(4)));
typedef f16   f16x8 __attribute__((ext_vector_type(8)));
typedef float f32x4 __attribute__((ext_vector_type(4)));

union H8 { f16x8 v; f16x4 h[2]; unsigned u[4]; };

// pack low halves of two cvt results into one VGPR of 2 f16 bit-patterns
__device__ __forceinline__ unsigned pkbits(unsigned lo, unsigned hi) {
    return __builtin_amdgcn_perm(hi, lo, 0x05040100); // bytes lo.0,lo.1,hi.0,hi.1
}

// ---------------------------------------------------------------------------
// Swapped-operand MFMA attention partials (no P round-trip through LDS),
// round-2 structure + DUAL-STREAM: each wave interleaves two independent key
// sub-ranges (kk and kk+SEGK/2) per iteration -> two dependency chains in
// flight, hiding ds_read/MFMA/cvt latency within a single wave (round-4
// post-mortem: kernel is stall-bound, not throughput-bound).
//   QK^T (swapped): S = mfma(A=K rows, B=Q cols, C=seed) -> D[key][query]:
//     lane holds col=query(lane&15), rows=keys 4ch+r; each lane owns 8 scores
//     of ONE query row = exactly the PV A-fragment ownership.
//   exp: v_cvt_u32_f32 (saturating) + v_perm pack -> PV A-frag in registers.
//   PV: G += mfma(PA, V', G) with k-slot permutation sigma(ch,s):
//     slots 0-3 = keys kk+4ch..+3, slots 4-7 = keys kk+16+4ch..+3, matched on
//     the B side by two ds_read_b64 from comp-major KTlds (pad +8 -> <=2-way).
//   Accumulator cols 0..3 = (L, G0, G1, G2); col 0 via V' comp row of ones.
// Fragment layouts identical to rounds 1-2 (validated):
//   A: row=lane&15, k=8ch+slot;  B: col=lane&15, k=8ch+slot;
//   C/D: col=lane&15, row=4ch+reg.
// s_setprio(1) around the MFMA+cvt cluster (independent-wave structure = the
// regime where setprio measured +4-7%, m191); ds_reads stay prio 0.
// LDS = SEGK*8 + 4*(SEGK+8)*2 bytes (8.3 KB at SEGK=512).
// ---------------------------------------------------------------------------
template <int SEGK_T>
__global__ __launch_bounds__(TPB) void attn_mfma_kernel(
    const float* __restrict__ x, const float* __restrict__ W,
    const float* __restrict__ bias, float4* __restrict__ part)
{
    __shared__ f16x4 Klds[SEGK_T];           // (x0,x1,x2,0) per key : QK A-frag
    __shared__ f16   KTlds[4][SEGK_T + 8];   // comps {1,x0,x1,x2}   : PV B-frag

    const int tid  = threadIdx.x;
    const int lane = tid & 63;
    const int w    = tid >> 6;
    const int seg  = blockIdx.x;
    const int qt   = blockIdx.y;
    const int b    = blockIdx.z;

    // ---- stage keys to LDS (f16) — round-2-validated scalar path ----
    const float* kbp = x + ((size_t)b * NN + (size_t)seg * SEGK_T) * 3;
    for (int i = tid; i < SEGK_T; i += TPB) {
        float k0 = kbp[3 * i], k1 = kbp[3 * i + 1], k2 = kbp[3 * i + 2];
        f16 h0 = (f16)k0, h1 = (f16)k1, h2 = (f16)k2;
        Klds[i] = (f16x4){h0, h1, h2, (f16)0.f};
        KTlds[0][i] = (f16)1.f;
        KTlds[1][i] = h0;
        KTlds[2][i] = h1;
        KTlds[3][i] = h2;
    }

    // ---- per-query prep (lane&31 carries query q0i + (lane&31)) ----
    float Wr[9][3], br[9];
#pragma unroll
    for (int c = 0; c < 9; ++c) {
        Wr[c][0] = W[3 * c]; Wr[c][1] = W[3 * c + 1]; Wr[c][2] = W[3 * c + 2];
        br[c] = bias[c];
    }
    const int q0i = qt * QBLK + w * QW;
    float qcs;                 // QS16*(q.bk) + B16C
    unsigned qp0, qp1;         // packed f16 {QS16*qt0, qt1}, {qt2, 0}
    {
        int ql = lane & 31;
        const float* xq = x + ((size_t)b * NN + q0i + ql) * 3;
        float x0 = xq[0], x1 = xq[1], x2 = xq[2];
        float a0 = fmaf(x0, Wr[0][0], fmaf(x1, Wr[0][1], fmaf(x2, Wr[0][2], br[0])));
        float a1 = fmaf(x0, Wr[3][0], fmaf(x1, Wr[3][1], fmaf(x2, Wr[3][2], br[3])));
        float a2 = fmaf(x0, Wr[6][0], fmaf(x1, Wr[6][1], fmaf(x2, Wr[6][2], br[6])));
        float t0 = QS16 * fmaf(a0, Wr[1][0], fmaf(a1, Wr[4][0], a2 * Wr[7][0]));
        float t1 = QS16 * fmaf(a0, Wr[1][1], fmaf(a1, Wr[4][1], a2 * Wr[7][1]));
        float t2 = QS16 * fmaf(a0, Wr[1][2], fmaf(a1, Wr[4][2], a2 * Wr[7][2]));
        qcs = fmaf(QS16, fmaf(a0, br[1], fmaf(a1, br[4], a2 * br[7])), B16C);
        f16x4 qh = (f16x4){(f16)t0, (f16)t1, (f16)t2, (f16)0.f};
        unsigned up[2];
        __builtin_memcpy(up, &qh, 8);
        qp0 = up[0]; qp1 = up[1];
    }

    const int li = lane & 15, ch = lane >> 4;

    // Q B-frags (hoisted, loop-invariant): col=query li (+16*t2), ch=0 slots
    // 0..2 = scaled comps, everything else zero. C-seed: all regs = qcs(query).
    H8 Bq[2];
    f32x4 qC[2];
#pragma unroll
    for (int t2 = 0; t2 < 2; ++t2) {
        int src = 16 * t2 + li;
        unsigned a0 = (unsigned)__shfl((int)qp0, src);
        unsigned a1 = (unsigned)__shfl((int)qp1, src);
        if (ch != 0) { a0 = 0u; a1 = 0u; }
        Bq[t2].u[0] = a0; Bq[t2].u[1] = a1; Bq[t2].u[2] = 0u; Bq[t2].u[3] = 0u;
        float cs = __shfl(qcs, src);
        qC[t2] = (f32x4){cs, cs, cs, cs};
    }

    __syncthreads();

    const f16x4* Ka    = &Klds[li];                 // A-frag rows
    const f16*   Vbase = &KTlds[lane & 3][4 * ch];  // PV B-frag (cols>=4 dup)

    constexpr int HALF = SEGK_T / 2;
    f32x4 Ga0 = {0.f, 0.f, 0.f, 0.f}, Ga1 = {0.f, 0.f, 0.f, 0.f};
    f32x4 Gb0 = {0.f, 0.f, 0.f, 0.f}, Gb1 = {0.f, 0.f, 0.f, 0.f};

#pragma unroll 2
    for (int kk = 0; kk < HALF; kk += KSTEP) {
        // ---- fragment loads for both streams (prio 0, batched ds_reads) ----
        H8 Aa0, Aa1, Va, Ab0, Ab1, Vb;
        Aa0.h[0] = Ka[kk];             Aa0.u[2] = 0u; Aa0.u[3] = 0u;
        Aa1.h[0] = Ka[kk + 16];        Aa1.u[2] = 0u; Aa1.u[3] = 0u;
        Va.h[0] = *(const f16x4*)(Vbase + kk);
        Va.h[1] = *(const f16x4*)(Vbase + kk + 16);
        Ab0.h[0] = Ka[HALF + kk];      Ab0.u[2] = 0u; Ab0.u[3] = 0u;
        Ab1.h[0] = Ka[HALF + kk + 16]; Ab1.u[2] = 0u; Ab1.u[3] = 0u;
        Vb.h[0] = *(const f16x4*)(Vbase + HALF + kk);
        Vb.h[1] = *(const f16x4*)(Vbase + HALF + kk + 16);

        __builtin_amdgcn_s_setprio(1);
        // ---- stream A ----
        {
            f32x4 S00 = __builtin_amdgcn_mfma_f32_16x16x32_f16(Aa0.v, Bq[0].v, qC[0], 0, 0, 0);
            f32x4 S10 = __builtin_amdgcn_mfma_f32_16x16x32_f16(Aa1.v, Bq[0].v, qC[0], 0, 0, 0);
            f32x4 S01 = __builtin_amdgcn_mfma_f32_16x16x32_f16(Aa0.v, Bq[1].v, qC[1], 0, 0, 0);
            f32x4 S11 = __builtin_amdgcn_mfma_f32_16x16x32_f16(Aa1.v, Bq[1].v, qC[1], 0, 0, 0);
            unsigned u00[4], u10[4], u01[4], u11[4];
#pragma unroll
            for (int r = 0; r < 4; ++r) {
                asm("v_cvt_u32_f32 %0, %1" : "=v"(u00[r]) : "v"(S00[r]));
                asm("v_cvt_u32_f32 %0, %1" : "=v"(u10[r]) : "v"(S10[r]));
                asm("v_cvt_u32_f32 %0, %1" : "=v"(u01[r]) : "v"(S01[r]));
                asm("v_cvt_u32_f32 %0, %1" : "=v"(u11[r]) : "v"(S11[r]));
            }
            H8 PA0, PA1;
            PA0.u[0] = pkbits(u00[0], u00[1]);  PA0.u[1] = pkbits(u00[2], u00[3]);
            PA0.u[2] = pkbits(u10[0], u10[1]);  PA0.u[3] = pkbits(u10[2], u10[3]);
            PA1.u[0] = pkbits(u01[0], u01[1]);  PA1.u[1] = pkbits(u01[2], u01[3]);
            PA1.u[2] = pkbits(u11[0], u11[1]);  PA1.u[3] = pkbits(u11[2], u11[3]);
            Ga0 = __builtin_amdgcn_mfma_f32_16x16x32_f16(PA0.v, Va.v, Ga0, 0, 0, 0);
            Ga1 = __builtin_amdgcn_mfma_f32_16x16x32_f16(PA1.v, Va.v, Ga1, 0, 0, 0);
        }
        // ---- stream B (independent chain) ----
        {
            f32x4 S00 = __builtin_amdgcn_mfma_f32_16x16x32_f16(Ab0.v, Bq[0].v, qC[0], 0, 0, 0);
            f32x4 S10 = __builtin_amdgcn_mfma_f32_16x16x32_f16(Ab1.v, Bq[0].v, qC[0], 0, 0, 0);
            f32x4 S01 = __builtin_amdgcn_mfma_f32_16x16x32_f16(Ab0.v, Bq[1].v, qC[1], 0, 0, 0);
            f32x4 S11 = __builtin_amdgcn_mfma_f32_16x16x32_f16(Ab1.v, Bq[1].v, qC[1], 0, 0, 0);
            unsigned u00[4], u10[4], u01[4], u11[4];
#pragma unroll
            for (int r = 0; r < 4; ++r) {
                asm("v_cvt_u32_f32 %0, %1" : "=v"(u00[r]) : "v"(S00[r]));
                asm("v_cvt_u32_f32 %0, %1" : "=v"(u10[r]) : "v"(S10[r]));
                asm("v_cvt_u32_f32 %0, %1" : "=v"(u01[r]) : "v"(S01[r]));
                asm("v_cvt_u32_f32 %0, %1" : "=v"(u11[r]) : "v"(S11[r]));
            }
            H8 PA0, PA1;
            PA0.u[0] = pkbits(u00[0], u00[1]);  PA0.u[1] = pkbits(u00[2], u00[3]);
            PA0.u[2] = pkbits(u10[0], u10[1]);  PA0.u[3] = pkbits(u10[2], u10[3]);
            PA1.u[0] = pkbits(u01[0], u01[1]);  PA1.u[1] = pkbits(u01[2], u01[3]);
            PA1.u[2] = pkbits(u11[0], u11[1]);  PA1.u[3] = pkbits(u11[2], u11[3]);
            Gb0 = __builtin_amdgcn_mfma_f32_16x16x32_f16(PA0.v, Vb.v, Gb0, 0, 0, 0);
            Gb1 = __builtin_amdgcn_mfma_f32_16x16x32_f16(PA1.v, Vb.v, Gb1, 0, 0, 0);
        }
        __builtin_amdgcn_s_setprio(0);
    }

    f32x4 G0 = Ga0 + Gb0;
    f32x4 G1 = Ga1 + Gb1;

    // ---- epilogue: G row=query 4ch+r (+16 for G1), col li = (L,G0,G1,G2) ----
    if (li < 4) {
        float* dst = (float*)(part + (size_t)seg * BN + (size_t)b * NN + q0i);
#pragma unroll
        for (int r = 0; r < 4; ++r) {
            dst[4 * (4 * ch + r) + li]      = G0[r];
            dst[4 * (16 + 4 * ch + r) + li] = G1[r];
        }
    }
}

// ---------------------------------------------------------------------------
// Combine partials, apply v-projection + residual:
//   out_c = Wv[c] . (G/L) + bv[c] + x_c   (Wv rows = qkv rows 2,5,8).
// ---------------------------------------------------------------------------
template <int NSEG_T>
__global__ __launch_bounds__(128) void combine_kernel(const float4* __restrict__ part,
                                                      const float* __restrict__ x,
                                                      const float* __restrict__ W,
                                                      const float* __restrict__ bias,
                                                      float* __restrict__ out)
{
    int q = blockIdx.x * 128 + threadIdx.x;   // 0 .. BN-1
    float L = 0.f, G0 = 0.f, G1 = 0.f, G2 = 0.f;
#pragma unroll
    for (int s = 0; s < NSEG_T; ++s) {
        float4 p = part[(size_t)s * BN + q];
        L += p.x; G0 += p.y; G1 += p.z; G2 += p.w;
    }
    float inv = 1.0f / L;
    float a0 = G0 * inv, a1 = G1 * inv, a2 = G2 * inv;
#pragma unroll
    for (int c = 0; c < 3; ++c) {
        int r = 3 * c + 2;  // Wv rows 2,5,8
        float o = fmaf(a0, W[3 * r], fmaf(a1, W[3 * r + 1],
                  fmaf(a2, W[3 * r + 2], bias[r])));
        out[3 * q + c] = o + x[3 * q + c];
    }
}

template <int NSEG_T>
static void launch_all(const float* x, const float* W, const float* bias,
                       float4* part, float* out, hipStream_t stream) {
    dim3 g(NSEG_T, NN / QBLK, BB);
    attn_mfma_kernel<NN / NSEG_T><<<g, TPB, 0, stream>>>(x, W, bias, part);
    combine_kernel<NSEG_T><<<BN / 128, 128, 0, stream>>>(part, x, W, bias, out);
}

extern "C" void kernel_launch(void* const* d_in, const int* in_sizes, int n_in,
                              void* d_out, int out_size, void* d_ws, size_t ws_size,
                              hipStream_t stream) {
    const float* x    = (const float*)d_in[0];  // (B, N, 3)
    const float* W    = (const float*)d_in[1];  // (9, 3)
    const float* bias = (const float*)d_in[2];  // (9,)
    float* out = (float*)d_out;                 // (B, N, 3)
    float4* part = (float4*)d_ws;

    size_t plane = (size_t)BN * 16;
    if (ws_size >= 16 * plane)      launch_all<16>(x, W, bias, part, out, stream);
    else if (ws_size >= 8 * plane)  launch_all<8>(x, W, bias, part, out, stream);
    else                            launch_all<4>(x, W, bias, part, out, stream);
}

// Round 6
// 88.615 us; speedup vs baseline: 1.0345x; 1.0209x over previous
//
#include <hip/hip_runtime.h>

// Problem constants (reference: B=4, N=8192, PIXEL_DIM=3).
#define BB   4
#define NN   8192
#define BN   (BB * NN)
#define TPB  256

#define QW    32               // queries per wave (2 MFMA col-tiles) — round-2 best
#define QBLK  (QW * 4)         // 128 queries per block (4 waves)
#define KSTEP 32               // keys per inner step

// f16-scale Schraudolph: u = QS16*(q.k + q.bk) + B16C; f16 bits = u16(sat_u32(u)).
// QS16 = 1024*log2(e)/sqrt(3); B16C = (15 - 8 - 0.03546)*1024. The 2^-8.04 scale
// on p and the interp-error systematic part cancel in G/L. Validated rounds 1-2
// (absmax 0.015625). u stays < 31744 (f16 inf) and < 65536 (u16); negatives
// saturate to 0 via v_cvt_u32_f32.
#define QS16  852.58618f
#define B16C  7131.651f

typedef _Float16 f16;
typedef f16   f16x4 __attribute__((ext_vector_type(4)));
typedef f16   f16x8 __attribute__((ext_vector_type(8)));
typedef float f32x4 __attribute__((ext_vector_type(4)));

union H8 { f16x8 v; f16x4 h[2]; unsigned u[4]; };

// pack low halves of two cvt results into one VGPR of 2 f16 bit-patterns
__device__ __forceinline__ unsigned pkbits(unsigned lo, unsigned hi) {
    return __builtin_amdgcn_perm(hi, lo, 0x05040100); // bytes lo.0,lo.1,hi.0,hi.1
}

// ---------------------------------------------------------------------------
// Swapped-operand MFMA attention partials (no P round-trip through LDS),
// round-2 structure + DEPTH-1 SOFTWARE PIPELINE: iteration k's compute runs
// while iteration k+1's LDS fragments are in flight (rounds 4-5 post-mortem:
// ~375 cyc/step measured vs ~65 cyc issue budget => the per-step serial chain
// ds_read -> lgkmcnt -> QK MFMA -> cvt -> PV was latency-bound and unhidden;
// prefetch moves the lgkmcnt wait one full compute-iteration later).
// No setprio / sched fences — they pin the compiler's schedule (round 5).
//   QK^T (swapped): S = mfma(A=K rows, B=Q cols, C=seed) -> D[key][query]:
//     lane holds col=query(lane&15), rows=keys 4ch+r; each lane owns 8 scores
//     of ONE query row = exactly the PV A-fragment ownership.
//   exp: v_cvt_u32_f32 (saturating) + v_perm pack -> PV A-frag in registers.
//   PV: G += mfma(PA, V', G) with k-slot permutation sigma(ch,s):
//     slots 0-3 = keys kk+4ch..+3, slots 4-7 = keys kk+16+4ch..+3, matched on
//     the B side by two ds_read_b64 from comp-major KTlds (pad +8 -> <=2-way).
//   Accumulator cols 0..3 = (L, G0, G1, G2); col 0 via V' comp row of ones.
// Fragment layouts identical to rounds 1-2 (validated):
//   A: row=lane&15, k=8ch+slot;  B: col=lane&15, k=8ch+slot;
//   C/D: col=lane&15, row=4ch+reg.
// LDS = SEGK*8 + 4*(SEGK+8)*2 bytes (16.4 KB at SEGK=1024) -> 8 blocks/CU.
// ---------------------------------------------------------------------------
template <int SEGK_T>
__global__ __launch_bounds__(TPB) void attn_mfma_kernel(
    const float* __restrict__ x, const float* __restrict__ W,
    const float* __restrict__ bias, float4* __restrict__ part)
{
    __shared__ f16x4 Klds[SEGK_T];           // (x0,x1,x2,0) per key : QK A-frag
    __shared__ f16   KTlds[4][SEGK_T + 8];   // comps {1,x0,x1,x2}   : PV B-frag

    const int tid  = threadIdx.x;
    const int lane = tid & 63;
    const int w    = tid >> 6;
    const int seg  = blockIdx.x;
    const int qt   = blockIdx.y;
    const int b    = blockIdx.z;

    // ---- stage keys to LDS (f16) — round-2-validated scalar path ----
    const float* kbp = x + ((size_t)b * NN + (size_t)seg * SEGK_T) * 3;
    for (int i = tid; i < SEGK_T; i += TPB) {
        float k0 = kbp[3 * i], k1 = kbp[3 * i + 1], k2 = kbp[3 * i + 2];
        f16 h0 = (f16)k0, h1 = (f16)k1, h2 = (f16)k2;
        Klds[i] = (f16x4){h0, h1, h2, (f16)0.f};
        KTlds[0][i] = (f16)1.f;
        KTlds[1][i] = h0;
        KTlds[2][i] = h1;
        KTlds[3][i] = h2;
    }

    // ---- per-query prep (lane&31 carries query q0i + (lane&31)) ----
    float Wr[9][3], br[9];
#pragma unroll
    for (int c = 0; c < 9; ++c) {
        Wr[c][0] = W[3 * c]; Wr[c][1] = W[3 * c + 1]; Wr[c][2] = W[3 * c + 2];
        br[c] = bias[c];
    }
    const int q0i = qt * QBLK + w * QW;
    float qcs;                 // QS16*(q.bk) + B16C
    unsigned qp0, qp1;         // packed f16 {QS16*qt0, qt1}, {qt2, 0}
    {
        int ql = lane & 31;
        const float* xq = x + ((size_t)b * NN + q0i + ql) * 3;
        float x0 = xq[0], x1 = xq[1], x2 = xq[2];
        float a0 = fmaf(x0, Wr[0][0], fmaf(x1, Wr[0][1], fmaf(x2, Wr[0][2], br[0])));
        float a1 = fmaf(x0, Wr[3][0], fmaf(x1, Wr[3][1], fmaf(x2, Wr[3][2], br[3])));
        float a2 = fmaf(x0, Wr[6][0], fmaf(x1, Wr[6][1], fmaf(x2, Wr[6][2], br[6])));
        float t0 = QS16 * fmaf(a0, Wr[1][0], fmaf(a1, Wr[4][0], a2 * Wr[7][0]));
        float t1 = QS16 * fmaf(a0, Wr[1][1], fmaf(a1, Wr[4][1], a2 * Wr[7][1]));
        float t2 = QS16 * fmaf(a0, Wr[1][2], fmaf(a1, Wr[4][2], a2 * Wr[7][2]));
        qcs = fmaf(QS16, fmaf(a0, br[1], fmaf(a1, br[4], a2 * br[7])), B16C);
        f16x4 qh = (f16x4){(f16)t0, (f16)t1, (f16)t2, (f16)0.f};
        unsigned up[2];
        __builtin_memcpy(up, &qh, 8);
        qp0 = up[0]; qp1 = up[1];
    }

    const int li = lane & 15, ch = lane >> 4;

    // Q B-frags (hoisted, loop-invariant): col=query li (+16*t2), ch=0 slots
    // 0..2 = scaled comps, everything else zero. C-seed: all regs = qcs(query).
    H8 Bq[2];
    f32x4 qC[2];
#pragma unroll
    for (int t2 = 0; t2 < 2; ++t2) {
        int src = 16 * t2 + li;
        unsigned a0 = (unsigned)__shfl((int)qp0, src);
        unsigned a1 = (unsigned)__shfl((int)qp1, src);
        if (ch != 0) { a0 = 0u; a1 = 0u; }
        Bq[t2].u[0] = a0; Bq[t2].u[1] = a1; Bq[t2].u[2] = 0u; Bq[t2].u[3] = 0u;
        float cs = __shfl(qcs, src);
        qC[t2] = (f32x4){cs, cs, cs, cs};
    }

    __syncthreads();

    const f16x4* Ka    = &Klds[li];                 // A-frag rows
    const f16*   Vbase = &KTlds[lane & 3][4 * ch];  // PV B-frag (cols>=4 dup)

    f32x4 G0 = {0.f, 0.f, 0.f, 0.f}, G1 = {0.f, 0.f, 0.f, 0.f};

    // ---- depth-1 pipelined K-loop ----
    f16x4 a0c = Ka[0], a1c = Ka[16];
    f16x4 v0c = *(const f16x4*)(Vbase + 0);
    f16x4 v1c = *(const f16x4*)(Vbase + 16);

#pragma unroll 2
    for (int kk = 0; kk < SEGK_T; kk += KSTEP) {
        const int nk = (kk + KSTEP) & (SEGK_T - 1);   // last iter: wraps to 0 (discarded)
        // prefetch next iteration's fragments (in flight during compute below)
        f16x4 a0n = Ka[nk], a1n = Ka[nk + 16];
        f16x4 v0n = *(const f16x4*)(Vbase + nk);
        f16x4 v1n = *(const f16x4*)(Vbase + nk + 16);

        H8 A0, A1, V;
        A0.h[0] = a0c; A0.u[2] = 0u; A0.u[3] = 0u;
        A1.h[0] = a1c; A1.u[2] = 0u; A1.u[3] = 0u;
        V.h[0] = v0c;  V.h[1] = v1c;

        f32x4 S00 = __builtin_amdgcn_mfma_f32_16x16x32_f16(A0.v, Bq[0].v, qC[0], 0, 0, 0);
        f32x4 S10 = __builtin_amdgcn_mfma_f32_16x16x32_f16(A1.v, Bq[0].v, qC[0], 0, 0, 0);
        f32x4 S01 = __builtin_amdgcn_mfma_f32_16x16x32_f16(A0.v, Bq[1].v, qC[1], 0, 0, 0);
        f32x4 S11 = __builtin_amdgcn_mfma_f32_16x16x32_f16(A1.v, Bq[1].v, qC[1], 0, 0, 0);

        unsigned u00[4], u10[4], u01[4], u11[4];
#pragma unroll
        for (int r = 0; r < 4; ++r) {
            asm("v_cvt_u32_f32 %0, %1" : "=v"(u00[r]) : "v"(S00[r]));
            asm("v_cvt_u32_f32 %0, %1" : "=v"(u10[r]) : "v"(S10[r]));
            asm("v_cvt_u32_f32 %0, %1" : "=v"(u01[r]) : "v"(S01[r]));
            asm("v_cvt_u32_f32 %0, %1" : "=v"(u11[r]) : "v"(S11[r]));
        }
        H8 PA0, PA1;
        PA0.u[0] = pkbits(u00[0], u00[1]);  PA0.u[1] = pkbits(u00[2], u00[3]);
        PA0.u[2] = pkbits(u10[0], u10[1]);  PA0.u[3] = pkbits(u10[2], u10[3]);
        PA1.u[0] = pkbits(u01[0], u01[1]);  PA1.u[1] = pkbits(u01[2], u01[3]);
        PA1.u[2] = pkbits(u11[0], u11[1]);  PA1.u[3] = pkbits(u11[2], u11[3]);

        G0 = __builtin_amdgcn_mfma_f32_16x16x32_f16(PA0.v, V.v, G0, 0, 0, 0);
        G1 = __builtin_amdgcn_mfma_f32_16x16x32_f16(PA1.v, V.v, G1, 0, 0, 0);

        // rotate pipeline registers
        a0c = a0n; a1c = a1n; v0c = v0n; v1c = v1n;
    }

    // ---- epilogue: G row=query 4ch+r (+16 for G1), col li = (L,G0,G1,G2) ----
    if (li < 4) {
        float* dst = (float*)(part + (size_t)seg * BN + (size_t)b * NN + q0i);
#pragma unroll
        for (int r = 0; r < 4; ++r) {
            dst[4 * (4 * ch + r) + li]      = G0[r];
            dst[4 * (16 + 4 * ch + r) + li] = G1[r];
        }
    }
}

// ---------------------------------------------------------------------------
// Combine partials, apply v-projection + residual:
//   out_c = Wv[c] . (G/L) + bv[c] + x_c   (Wv rows = qkv rows 2,5,8).
// ---------------------------------------------------------------------------
template <int NSEG_T>
__global__ __launch_bounds__(128) void combine_kernel(const float4* __restrict__ part,
                                                      const float* __restrict__ x,
                                                      const float* __restrict__ W,
                                                      const float* __restrict__ bias,
                                                      float* __restrict__ out)
{
    int q = blockIdx.x * 128 + threadIdx.x;   // 0 .. BN-1
    float L = 0.f, G0 = 0.f, G1 = 0.f, G2 = 0.f;
#pragma unroll
    for (int s = 0; s < NSEG_T; ++s) {
        float4 p = part[(size_t)s * BN + q];
        L += p.x; G0 += p.y; G1 += p.z; G2 += p.w;
    }
    float inv = 1.0f / L;
    float a0 = G0 * inv, a1 = G1 * inv, a2 = G2 * inv;
#pragma unroll
    for (int c = 0; c < 3; ++c) {
        int r = 3 * c + 2;  // Wv rows 2,5,8
        float o = fmaf(a0, W[3 * r], fmaf(a1, W[3 * r + 1],
                  fmaf(a2, W[3 * r + 2], bias[r])));
        out[3 * q + c] = o + x[3 * q + c];
    }
}

template <int NSEG_T>
static void launch_all(const float* x, const float* W, const float* bias,
                       float4* part, float* out, hipStream_t stream) {
    dim3 g(NSEG_T, NN / QBLK, BB);
    attn_mfma_kernel<NN / NSEG_T><<<g, TPB, 0, stream>>>(x, W, bias, part);
    combine_kernel<NSEG_T><<<BN / 128, 128, 0, stream>>>(part, x, W, bias, out);
}

extern "C" void kernel_launch(void* const* d_in, const int* in_sizes, int n_in,
                              void* d_out, int out_size, void* d_ws, size_t ws_size,
                              hipStream_t stream) {
    const float* x    = (const float*)d_in[0];  // (B, N, 3)
    const float* W    = (const float*)d_in[1];  // (9, 3)
    const float* bias = (const float*)d_in[2];  // (9,)
    float* out = (float*)d_out;                 // (B, N, 3)
    float4* part = (float4*)d_ws;

    size_t plane = (size_t)BN * 16;
    if (ws_size >= 8 * plane)      launch_all<8>(x, W, bias, part, out, stream);
    else                           launch_all<4>(x, W, bias, part, out, stream);
}